// Round 7
// baseline (676.808 us; speedup 1.0000x reference)
//
#include <hip/hip_runtime.h>

typedef float v2f __attribute__((ext_vector_type(2)));

#define T_LEN 512
#define INP 5
#define HID 32

__device__ __forceinline__ v2f pkfma(v2f a, v2f b, v2f c) {
    return __builtin_elementwise_fma(a, b, c);
}

__device__ __forceinline__ float rdlane(float v, int j) {
    return __int_as_float(__builtin_amdgcn_readlane(__float_as_int(v), j));
}

// One wave per batch element. R6 bit-exact DAG; transport changes only:
//  - h0 broadcast via v_readlane -> uniform registers (no LDS round-trip)
//  - h1 via LDS (16 uniform b64 reads/step), unconditional write
//  - no __syncthreads (single-wave block, same-wave DS ops are in-order)
__global__ __launch_bounds__(64, 1) void lstm2_fused(
    const float* __restrict__ x,
    const float* __restrict__ Wih0, const float* __restrict__ Whh0,
    const float* __restrict__ bih0, const float* __restrict__ bhh0,
    const float* __restrict__ Wih1, const float* __restrict__ Whh1,
    const float* __restrict__ bih1, const float* __restrict__ bhh1,
    const float* __restrict__ Wfc,  const float* __restrict__ bfc,
    float* __restrict__ out)
{
    const int b = blockIdx.x;
    const int l = threadIdx.x;        // 0..63
    const int glo = l, ghi = l + 64;  // this lane's two gate rows (of 128)
    const bool isIG = (l < 32);       // lanes<32: (i,g); lanes>=32: (f,o)

    __shared__ __align__(16) float xs[T_LEN][8];   // 16 KB staged input
    __shared__ __align__(16) float h1s[HID];

    // ---- stage x[b] into LDS, coalesced (single wave: in-order, no barrier) ----
    const float* xb = x + (size_t)b * (T_LEN * INP);
    for (int idx = l; idx < T_LEN * INP; idx += 64) {
        const int t = idx / INP;
        const int d = idx - t * INP;
        xs[t][d] = xb[idx];
    }

    // ---- weights register-resident as v2f over j-pairs ----
    v2f whh0_lo[16], whh0_hi[16], wih1_lo[16], wih1_hi[16], whh1_lo[16], whh1_hi[16];
#define LOADW(dst_lo, dst_hi, W) { \
    const v2f* rlo_ = (const v2f*)((W) + glo * HID); \
    const v2f* rhi_ = (const v2f*)((W) + ghi * HID); \
    _Pragma("unroll") \
    for (int q = 0; q < 16; ++q) { \
        dst_lo[q] = rlo_[q]; \
        dst_hi[q] = rhi_[q]; \
    } }
    LOADW(whh0_lo, whh0_hi, Whh0)
    LOADW(wih1_lo, wih1_hi, Wih1)
    LOADW(whh1_lo, whh1_hi, Whh1)
#undef LOADW

    v2f wxlo01, wxlo23, wxhi01, wxhi23;
    float wxlo4, wxhi4;
    {
        const float* rl = Wih0 + glo * INP;
        const float* rh = Wih0 + ghi * INP;
        wxlo01 = (v2f){rl[0], rl[1]}; wxlo23 = (v2f){rl[2], rl[3]}; wxlo4 = rl[4];
        wxhi01 = (v2f){rh[0], rh[1]}; wxhi23 = (v2f){rh[2], rh[3]}; wxhi4 = rh[4];
    }

    const float bias0_lo = bih0[glo] + bhh0[glo];
    const float bias0_hi = bih0[ghi] + bhh0[ghi];
    const float bias1_lo = bih1[glo] + bhh1[glo];
    const float bias1_hi = bih1[ghi] + bhh1[ghi];

    // activations: sigmoid(v) = rcp(1+exp2(-log2e*v)); tanh(v) = 2*rcp(1+exp2(-2log2e*v))-1
    const float NL2E  = -1.4426950408889634f;
    const float NL2E2 = -2.8853900817779268f;
    const float kk_hi = isIG ? NL2E2 : NL2E;    // g: tanh, o: sigmoid
    const float sc_hi = isIG ?  2.0f : 1.0f;
    const float bb_hi = isIG ? -1.0f : 0.0f;

    float c0 = 0.0f, c1 = 0.0f, h1last = 0.0f;

    // h0_{t-1} broadcast registers (wave-uniform; bit-identical to old LDS path)
    v2f hb0[16];
    #pragma unroll
    for (int q = 0; q < 16; ++q) hb0[q] = (v2f)0.0f;

    h1s[l & 31] = 0.0f;                 // lanes m and m+32 write identical value

    const v2f* h12 = (const v2f*)h1s;   // 16 v2f, uniform-address reads

#define RED(a0, a1) ({ v2f s_ = (a0) + (a1); s_.x + s_.y; })

    for (int t = 0; t < T_LEN; ++t) {
        // ---- x_t from LDS (uniform broadcast reads) ----
        v2f xv01 = *(const v2f*)&xs[t][0];
        v2f xv23 = *(const v2f*)&xs[t][2];
        float x4 = xs[t][4];

        // ================= layer 0 (same chains/order as R6) =================
        v2f aL0 = pkfma(wxlo01, xv01, (v2f){bias0_lo, 0.0f});
        v2f aL1 = pkfma(wxlo23, xv23, (v2f){wxlo4 * x4, 0.0f});
        v2f aH0 = pkfma(wxhi01, xv01, (v2f){bias0_hi, 0.0f});
        v2f aH1 = pkfma(wxhi23, xv23, (v2f){wxhi4 * x4, 0.0f});
        #pragma unroll
        for (int r = 0; r < 8; ++r) {
            v2f hp0 = hb0[2*r];                  // uniform regs (was ds_read_b64)
            v2f hp1 = hb0[2*r+1];
            aL0 = pkfma(whh0_lo[2*r],   hp0, aL0);
            aL1 = pkfma(whh0_lo[2*r+1], hp1, aL1);
            aH0 = pkfma(whh0_hi[2*r],   hp0, aH0);
            aH1 = pkfma(whh0_hi[2*r+1], hp1, aH1);
        }
        float gl = RED(aL0, aL1);
        float gh = RED(aH0, aH1);

        float actL = __builtin_amdgcn_rcpf(1.0f + exp2f(NL2E * gl));             // sigmoid
        float actH = fmaf(sc_hi, __builtin_amdgcn_rcpf(1.0f + exp2f(kk_hi * gh)), bb_hi);
        float actLs = __shfl_xor(actL, 32);
        float actHs = __shfl_xor(actH, 32);
        float i_ = isIG ? actL  : actLs;
        float f_ = isIG ? actLs : actL;
        float g_ = isIG ? actH  : actHs;
        float o_ = isIG ? actHs : actH;
        c0 = fmaf(f_, c0, i_ * g_);
        float th0 = fmaf(2.0f, __builtin_amdgcn_rcpf(1.0f + exp2f(NL2E2 * c0)), -1.0f);
        float h0new = o_ * th0;

        // ---- broadcast h0_t into uniform registers (lane j holds h0[j], j<32) ----
        #pragma unroll
        for (int q = 0; q < 16; ++q) {
            hb0[q] = (v2f){ rdlane(h0new, 2*q), rdlane(h0new, 2*q + 1) };
        }

        // ================= layer 1 (single fused accumulation, R6 order) =================
        v2f bL0 = (v2f){bias1_lo, 0.0f}, bL1 = (v2f)0.0f;
        v2f bH0 = (v2f){bias1_hi, 0.0f}, bH1 = (v2f)0.0f;
        #pragma unroll
        for (int r = 0; r < 8; ++r) {
            v2f hp0 = hb0[2*r];                  // h0_t (fresh, uniform regs)
            v2f hp1 = hb0[2*r+1];
            bL0 = pkfma(wih1_lo[2*r],   hp0, bL0);
            bL1 = pkfma(wih1_lo[2*r+1], hp1, bL1);
            bH0 = pkfma(wih1_hi[2*r],   hp0, bH0);
            bH1 = pkfma(wih1_hi[2*r+1], hp1, bH1);
        }
        #pragma unroll
        for (int r = 0; r < 8; ++r) {
            v2f hp0 = h12[2*r];                  // h1_{t-1} from LDS (uniform b64)
            v2f hp1 = h12[2*r+1];
            bL0 = pkfma(whh1_lo[2*r],   hp0, bL0);
            bL1 = pkfma(whh1_lo[2*r+1], hp1, bL1);
            bH0 = pkfma(whh1_hi[2*r],   hp0, bH0);
            bH1 = pkfma(whh1_hi[2*r+1], hp1, bH1);
        }
        float gl1 = RED(bL0, bL1);
        float gh1 = RED(bH0, bH1);

        float actL1 = __builtin_amdgcn_rcpf(1.0f + exp2f(NL2E * gl1));
        float actH1 = fmaf(sc_hi, __builtin_amdgcn_rcpf(1.0f + exp2f(kk_hi * gh1)), bb_hi);
        float actL1s = __shfl_xor(actL1, 32);
        float actH1s = __shfl_xor(actH1, 32);
        float i1 = isIG ? actL1  : actL1s;
        float f1 = isIG ? actL1s : actL1;
        float g1 = isIG ? actH1  : actH1s;
        float o1 = isIG ? actH1s : actH1;
        c1 = fmaf(f1, c1, i1 * g1);
        float th1 = fmaf(2.0f, __builtin_amdgcn_rcpf(1.0f + exp2f(NL2E2 * c1)), -1.0f);
        h1last = o1 * th1;
        h1s[l & 31] = h1last;                    // same-wave in-order; dup lanes identical
    }
#undef RED

    // ---- final linear head ----
    const int m = l & 31;
    float p0 = isIG ? (Wfc[m]       * h1last) : 0.0f;
    float p1 = isIG ? (Wfc[HID + m] * h1last) : 0.0f;
    #pragma unroll
    for (int off = 32; off >= 1; off >>= 1) {
        p0 += __shfl_xor(p0, off);
        p1 += __shfl_xor(p1, off);
    }
    if (l == 0) {
        out[2 * b + 0] = p0 + bfc[0];
        out[2 * b + 1] = p1 + bfc[1];
    }
}

extern "C" void kernel_launch(void* const* d_in, const int* in_sizes, int n_in,
                              void* d_out, int out_size, void* d_ws, size_t ws_size,
                              hipStream_t stream) {
    const float* x    = (const float*)d_in[0];
    const float* Wih0 = (const float*)d_in[1];
    const float* Whh0 = (const float*)d_in[2];
    const float* bih0 = (const float*)d_in[3];
    const float* bhh0 = (const float*)d_in[4];
    const float* Wih1 = (const float*)d_in[5];
    const float* Whh1 = (const float*)d_in[6];
    const float* bih1 = (const float*)d_in[7];
    const float* bhh1 = (const float*)d_in[8];
    const float* Wfc  = (const float*)d_in[9];
    const float* bfc  = (const float*)d_in[10];
    float* out = (float*)d_out;

    const int nb = in_sizes[0] / (T_LEN * INP);   // 2048 batch elements
    lstm2_fused<<<dim3(nb), dim3(64), 0, stream>>>(
        x, Wih0, Whh0, bih0, bhh0, Wih1, Whh1, bih1, bhh1, Wfc, bfc, out);
}